// Round 6
// baseline (76.460 us; speedup 1.0000x reference)
//
#include <hip/hip_runtime.h>

typedef __attribute__((ext_vector_type(8))) short short8;
typedef __attribute__((ext_vector_type(4))) float f32x4;

#define B_TOTAL 20000
#define BT      16          // b-rows per block; 20000 = 1250*16 exactly
#define NBLK    1250
#define NF      256
#define K2      512
#define NS      10
#define N_NODES 100000

__device__ __forceinline__ unsigned short f2bf(float x) {
    unsigned u = __builtin_bit_cast(unsigned, x);
    u += 0x7FFFu + ((u >> 16) & 1u);   // round-to-nearest-even
    return (unsigned short)(u >> 16);
}
__device__ __forceinline__ float bf2f(unsigned short u) {
    return __builtin_bit_cast(float, ((unsigned)u) << 16);
}

// Prep: blocks 0..12499 convert ue f32->bf16 (8 elems/thread);
//       blocks 12500..12627 convert W f32->bf16 (4 elems/thread).
__global__ __launch_bounds__(256) void prep(
    const float* __restrict__ ue, const float* __restrict__ w,
    unsigned short* __restrict__ ueb, unsigned short* __restrict__ wbf)
{
    const int t = threadIdx.x, blk = blockIdx.x;
    if (blk < 12500) {                       // 12500*256*8 = 25,600,000 = 100000*256
        const size_t i = ((size_t)blk * 256 + t) * 8;
        const float4 v0 = *(const float4*)(ue + i);
        const float4 v1 = *(const float4*)(ue + i + 4);
        short8 o;
        o[0] = (short)f2bf(v0.x); o[1] = (short)f2bf(v0.y);
        o[2] = (short)f2bf(v0.z); o[3] = (short)f2bf(v0.w);
        o[4] = (short)f2bf(v1.x); o[5] = (short)f2bf(v1.y);
        o[6] = (short)f2bf(v1.z); o[7] = (short)f2bf(v1.w);
        *(short8*)(ueb + i) = o;
    } else {                                 // 128*256*4 = 131072 = 256*512 W elems
        const int base = (blk - 12500) * 1024 + t * 4;
        const float4 v = *(const float4*)(w + base);
        ushort4 o;
        o.x = f2bf(v.x); o.y = f2bf(v.y); o.z = f2bf(v.z); o.w = f2bf(v.w);
        *(ushort4*)(wbf + base) = o;
    }
}

// Standalone W convert (fallback path when ws can't hold ueb)
__global__ __launch_bounds__(256) void wconvert(const float* __restrict__ w,
                                                unsigned short* __restrict__ wbf) {
    const int i = (blockIdx.x * 256 + threadIdx.x) * 4;
    const float4 v = *(const float4*)(w + i);
    ushort4 o;
    o.x = f2bf(v.x); o.y = f2bf(v.y); o.z = f2bf(v.z); o.w = f2bf(v.w);
    *(ushort4*)(wbf + i) = o;
}

// Fused: gather 16 b-rows into swizzled LDS, one barrier, then 256e x 16b GEMM.
// UEB=1: gather from bf16 ue copy (512B rows); UEB=0: from f32 ue (1KB rows).
// LDS comb: [row 16][1024 B], logical byte ^ ((row&7)<<4).
template<int UEB>
__global__ __launch_bounds__(256, 4) void fused(
    const void* __restrict__ uev, const int* __restrict__ nidx,
    const int* __restrict__ nodes, const unsigned short* __restrict__ wbf,
    float* __restrict__ out)
{
    __shared__ unsigned short comb[BT * K2];   // 16 KB
    const int t    = threadIdx.x;
    const int lane = t & 63;
    const int wv   = t >> 6;
    const int bbase = blockIdx.x * BT;

    // ---- Phase 1: each wave gathers 4 rows ----
    {
        const int r0 = wv * 4;
        const int b0 = bbase + r0;
        int nv = 0;
        if (lane < 40)      nv = nidx[b0 * NS + lane];
        else if (lane < 44) nv = nodes[b0 + (lane - 40)];

        for (int r = 0; r < 4; ++r) {
            const int row = r0 + r;
            const int nd  = __shfl(nv, 40 + r);
            const int swz = (row & 7) << 4;
            char* base = (char*)comb + row * 1024;
            float ax = 0.f, ay = 0.f, az = 0.f, aw = 0.f;
            if (UEB) {
                const unsigned short* ueb = (const unsigned short*)uev;
                const ushort4 sv = ((const ushort4*)(ueb + (size_t)nd * NF))[lane];
                #pragma unroll
                for (int s = 0; s < NS; ++s) {
                    const int is = __shfl(nv, r * NS + s);
                    const ushort4 a = ((const ushort4*)(ueb + (size_t)is * NF))[lane];
                    ax += bf2f(a.x); ay += bf2f(a.y); az += bf2f(a.z); aw += bf2f(a.w);
                }
                *(ushort4*)(base + ((lane * 8) ^ swz)) = sv;      // self half (k<256)
            } else {
                const float* ue = (const float*)uev;
                const float4 sf = ((const float4*)(ue + (size_t)nd * NF))[lane];
                #pragma unroll
                for (int s = 0; s < NS; ++s) {
                    const int is = __shfl(nv, r * NS + s);
                    const float4 v = ((const float4*)(ue + (size_t)is * NF))[lane];
                    ax += v.x; ay += v.y; az += v.z; aw += v.w;
                }
                ushort4 s4;
                s4.x = f2bf(sf.x); s4.y = f2bf(sf.y);
                s4.z = f2bf(sf.z); s4.w = f2bf(sf.w);
                *(ushort4*)(base + ((lane * 8) ^ swz)) = s4;
            }
            const float inv = 1.0f / 11.0f;    // reference divides by S+1
            ushort4 n4;
            n4.x = f2bf(ax * inv); n4.y = f2bf(ay * inv);
            n4.z = f2bf(az * inv); n4.w = f2bf(aw * inv);
            *(ushort4*)(base + ((512 + lane * 8) ^ swz)) = n4;    // neigh half
        }
    }
    __syncthreads();

    // ---- Phase 2: GEMM, no barriers. Wave wv owns e-rows [wv*64, wv*64+64). ----
    const int fr = lane & 15;
    const int kq = lane >> 4;
    const unsigned short* wp = wbf + (size_t)(wv * 64 + fr) * K2 + kq * 8;
    const char* cbase = (const char*)comb + fr * 1024;
    const int swzR = (fr & 7) << 4;

    f32x4 acc[4] = {};
    #pragma unroll 4
    for (int ks = 0; ks < 16; ++ks) {
        const short8 bg = *(const short8*)(cbase + ((ks * 64 + kq * 16) ^ swzR));
        short8 af[4];
        #pragma unroll
        for (int i = 0; i < 4; ++i)
            af[i] = *(const short8*)(wp + (size_t)i * 16 * K2 + ks * 32);
        #pragma unroll
        for (int i = 0; i < 4; ++i)
            acc[i] = __builtin_amdgcn_mfma_f32_16x16x32_bf16(af[i], bg, acc[i], 0, 0, 0);
    }

    // ---- Epilogue: relu + store ----
    const int col = bbase + fr;
    #pragma unroll
    for (int i = 0; i < 4; ++i) {
        const int e = wv * 64 + i * 16 + kq * 4;
        #pragma unroll
        for (int r = 0; r < 4; ++r)
            out[(size_t)(e + r) * B_TOTAL + col] = fmaxf(acc[i][r], 0.0f);
    }
}

extern "C" void kernel_launch(void* const* d_in, const int* in_sizes, int n_in,
                              void* d_out, int out_size, void* d_ws, size_t ws_size,
                              hipStream_t stream) {
    const float* ue    = (const float*)d_in[0];
    // d_in[1] = features_ap: unused (ue2ue mode)
    const int*   nidx  = (const int*)d_in[2];
    const int*   nodes = (const int*)d_in[3];
    const float* w     = (const float*)d_in[4];
    float*       out   = (float*)d_out;

    const size_t ueb_elems = (size_t)N_NODES * NF;             // 25.6M ushorts
    const size_t need = (ueb_elems + 256 * K2) * sizeof(unsigned short);

    if (ws_size >= need) {
        unsigned short* ueb = (unsigned short*)d_ws;           // 51.2 MB
        unsigned short* wbf = ueb + ueb_elems;                 // 0.26 MB
        hipLaunchKernelGGL(prep, dim3(12628), dim3(256), 0, stream, ue, w, ueb, wbf);
        hipLaunchKernelGGL((fused<1>), dim3(NBLK), dim3(256), 0, stream,
                           (const void*)ueb, nidx, nodes, wbf, out);
    } else {                                                   // fallback: R5 proven path
        unsigned short* wbf = (unsigned short*)d_ws;
        hipLaunchKernelGGL(wconvert, dim3(128), dim3(256), 0, stream, w, wbf);
        hipLaunchKernelGGL((fused<0>), dim3(NBLK), dim3(256), 0, stream,
                           (const void*)ue, nidx, nodes, wbf, out);
    }
}

// Round 7
// 64.743 us; speedup vs baseline: 1.1810x; 1.1810x over previous
//
#include <hip/hip_runtime.h>

typedef __attribute__((ext_vector_type(8))) short short8;
typedef __attribute__((ext_vector_type(4))) float f32x4;

#define B_TOTAL 20000
#define B_PAD   20096   // 314 * 64 = 5024 * 4
#define NF      256
#define K2      512
#define NS      10

__device__ __forceinline__ unsigned short f2bf(float x) {
    unsigned u = __builtin_bit_cast(unsigned, x);
    u += 0x7FFFu + ((u >> 16) & 1u);   // round-to-nearest-even
    return (unsigned short)(u >> 16);
}

// K1 (R1-proven, untouched): one wave per b-row; 11 independent 1KB row loads
// in flight; coalesced bf16 row write. Blocks 0..127 also convert W f32->bf16.
__global__ __launch_bounds__(256) void gather_combine(
    const float* __restrict__ ue, const int* __restrict__ nidx,
    const int* __restrict__ nodes, const float* __restrict__ w,
    unsigned short* __restrict__ comb, unsigned short* __restrict__ wbf)
{
    const int t = threadIdx.x, blk = blockIdx.x;
    if (blk < 128) {                       // 128 * 256 * 4 = 256*512 W elems
        const int base = blk * 1024 + t * 4;
        const float4 v = *(const float4*)(w + base);
        ushort4 o;
        o.x = f2bf(v.x); o.y = f2bf(v.y); o.z = f2bf(v.z); o.w = f2bf(v.w);
        *(ushort4*)(wbf + base) = o;
    }
    const int lane = t & 63;
    const int b = blk * 4 + (t >> 6);      // one wave per b-row
    if (b >= B_PAD) return;
    unsigned short* crow = comb + (size_t)b * K2;
    if (b < B_TOTAL) {
        const int node = nodes[b];
        const float4 sf = ((const float4*)(ue + (size_t)node * NF))[lane];
        int myidx = 0;
        if (lane < NS) myidx = nidx[b * NS + lane];
        float ax = 0.f, ay = 0.f, az = 0.f, aw = 0.f;
        #pragma unroll
        for (int s = 0; s < NS; ++s) {
            const int is = __shfl(myidx, s);
            const float4 v = ((const float4*)(ue + (size_t)is * NF))[lane];
            ax += v.x; ay += v.y; az += v.z; aw += v.w;
        }
        const float inv = 1.0f / 11.0f;    // reference divides by S+1
        ushort4 s4, n4;
        s4.x = f2bf(sf.x); s4.y = f2bf(sf.y); s4.z = f2bf(sf.z); s4.w = f2bf(sf.w);
        n4.x = f2bf(ax * inv); n4.y = f2bf(ay * inv);
        n4.z = f2bf(az * inv); n4.w = f2bf(aw * inv);
        *(ushort4*)(crow + lane * 4) = s4;
        *(ushort4*)(crow + NF + lane * 4) = n4;
    } else {                               // zero pad rows (ws is poisoned)
        ushort4 z; z.x = z.y = z.z = z.w = 0;
        *(ushort4*)(crow + lane * 4) = z;
        *(ushort4*)(crow + NF + lane * 4) = z;
    }
}

// K2: out[e][b] = relu(sum_k W[e][k]*comb[b][k]).
// Tile 64(b) x 256(e), FULL K=512 B-tile resident in LDS (64 KB), staged once.
// Split-stage: counted vmcnt(8) + raw s_barrier -> compute ks 0..7 overlaps the
// second 32 KB in flight. K-loop itself is barrier-free; W direct from L2.
// LDS layout [kg 64][row 64][8 bf16]; grid 314 = 20096/64.
__global__ __launch_bounds__(256) void gemm_relu(
    const unsigned short* __restrict__ wbf,   // [256][512] bf16
    const unsigned short* __restrict__ comb,  // [B_PAD][512] bf16
    float* __restrict__ out)                  // [256][20000] f32
{
    __shared__ unsigned short Blds[64 * K2];  // 64 KB
    const int t    = threadIdx.x;
    const int lane = t & 63;
    const int wv   = t >> 6;                  // wave owns e-rows [wv*64, wv*64+64)
    const int n0   = blockIdx.x * 64;
    const int fr   = lane & 15;
    const int kq   = lane >> 4;

    // ---- stage all 64 KB: wave wv, iter L -> kg = L*4+wv, rows = lane ----
    #pragma unroll
    for (int L = 0; L < 16; ++L) {
        const int kg = L * 4 + wv;
        const unsigned short* src = comb + (size_t)(n0 + lane) * K2 + kg * 8;
        __builtin_amdgcn_global_load_lds(
            (const __attribute__((address_space(1))) void*)src,
            (__attribute__((address_space(3))) void*)(Blds + ((size_t)kg * 64 + lane) * 8),
            16, 0, 0);
    }

    // first half ready: oldest 8 issues (L=0..7 -> kg 0..31) complete
    asm volatile("s_waitcnt vmcnt(8)" ::: "memory");
    __builtin_amdgcn_s_barrier();
    __builtin_amdgcn_sched_barrier(0);

    const unsigned short* wp = wbf + (size_t)(wv * 64 + fr) * K2 + kq * 8;
    const short8* B8 = (const short8*)Blds;
    f32x4 acc[4][4] = {};

    #pragma unroll 4
    for (int ks = 0; ks < 8; ++ks) {
        short8 af[4], bg[4];
        #pragma unroll
        for (int i = 0; i < 4; ++i)
            af[i] = *(const short8*)(wp + (size_t)i * 16 * K2 + ks * 32);
        #pragma unroll
        for (int j = 0; j < 4; ++j)
            bg[j] = B8[(ks * 4 + kq) * 64 + j * 16 + fr];
        #pragma unroll
        for (int i = 0; i < 4; ++i)
            #pragma unroll
            for (int j = 0; j < 4; ++j)
                acc[i][j] = __builtin_amdgcn_mfma_f32_16x16x32_bf16(af[i], bg[j], acc[i][j], 0, 0, 0);
    }

    // second half ready
    asm volatile("s_waitcnt vmcnt(0)" ::: "memory");
    __builtin_amdgcn_s_barrier();
    __builtin_amdgcn_sched_barrier(0);

    #pragma unroll 4
    for (int ks = 8; ks < 16; ++ks) {
        short8 af[4], bg[4];
        #pragma unroll
        for (int i = 0; i < 4; ++i)
            af[i] = *(const short8*)(wp + (size_t)i * 16 * K2 + ks * 32);
        #pragma unroll
        for (int j = 0; j < 4; ++j)
            bg[j] = B8[(ks * 4 + kq) * 64 + j * 16 + fr];
        #pragma unroll
        for (int i = 0; i < 4; ++i)
            #pragma unroll
            for (int j = 0; j < 4; ++j)
                acc[i][j] = __builtin_amdgcn_mfma_f32_16x16x32_bf16(af[i], bg[j], acc[i][j], 0, 0, 0);
    }

    // ---- epilogue: relu + store ----
    #pragma unroll
    for (int i = 0; i < 4; ++i) {
        const int e = wv * 64 + i * 16 + kq * 4;
        #pragma unroll
        for (int j = 0; j < 4; ++j) {
            const int b = n0 + j * 16 + fr;
            if (b < B_TOTAL) {
                #pragma unroll
                for (int r = 0; r < 4; ++r)
                    out[(size_t)(e + r) * B_TOTAL + b] = fmaxf(acc[i][j][r], 0.0f);
            }
        }
    }
}

extern "C" void kernel_launch(void* const* d_in, const int* in_sizes, int n_in,
                              void* d_out, int out_size, void* d_ws, size_t ws_size,
                              hipStream_t stream) {
    const float* ue    = (const float*)d_in[0];
    // d_in[1] = features_ap: unused (ue2ue mode)
    const int*   nidx  = (const int*)d_in[2];
    const int*   nodes = (const int*)d_in[3];
    const float* w     = (const float*)d_in[4];
    float*       out   = (float*)d_out;

    unsigned short* comb = (unsigned short*)d_ws;              // [B_PAD][512] bf16 = 20.58 MB
    unsigned short* wbf  = comb + (size_t)B_PAD * K2;          // [256][512] bf16  = 0.26 MB

    hipLaunchKernelGGL(gather_combine, dim3(B_PAD / 4), dim3(256), 0, stream,
                       ue, nidx, nodes, w, comb, wbf);
    hipLaunchKernelGGL(gemm_relu, dim3(B_PAD / 64), dim3(256), 0, stream,
                       wbf, comb, out);
}

// Round 8
// 61.555 us; speedup vs baseline: 1.2421x; 1.0518x over previous
//
#include <hip/hip_runtime.h>

typedef __attribute__((ext_vector_type(8))) short short8;
typedef __attribute__((ext_vector_type(4))) float f32x4;

#define B_TOTAL 20000
#define B_PAD   20096   // 314 * 64 = 5024 * 4
#define NF      256
#define K2      512
#define NS      10

__device__ __forceinline__ unsigned short f2bf(float x) {
    unsigned u = __builtin_bit_cast(unsigned, x);
    u += 0x7FFFu + ((u >> 16) & 1u);   // round-to-nearest-even
    return (unsigned short)(u >> 16);
}

// K1 (R1-proven, bit-identical): one wave per b-row; 11 independent 1KB row
// loads in flight; coalesced bf16 row write. Blocks 0..127 also convert W.
__global__ __launch_bounds__(256) void gather_combine(
    const float* __restrict__ ue, const int* __restrict__ nidx,
    const int* __restrict__ nodes, const float* __restrict__ w,
    unsigned short* __restrict__ comb, unsigned short* __restrict__ wbf)
{
    const int t = threadIdx.x, blk = blockIdx.x;
    if (blk < 128) {                       // 128 * 256 * 4 = 256*512 W elems
        const int base = blk * 1024 + t * 4;
        const float4 v = *(const float4*)(w + base);
        ushort4 o;
        o.x = f2bf(v.x); o.y = f2bf(v.y); o.z = f2bf(v.z); o.w = f2bf(v.w);
        *(ushort4*)(wbf + base) = o;
    }
    const int lane = t & 63;
    const int b = blk * 4 + (t >> 6);      // one wave per b-row
    if (b >= B_PAD) return;
    unsigned short* crow = comb + (size_t)b * K2;
    if (b < B_TOTAL) {
        const int node = nodes[b];
        const float4 sf = ((const float4*)(ue + (size_t)node * NF))[lane];
        int myidx = 0;
        if (lane < NS) myidx = nidx[b * NS + lane];
        float ax = 0.f, ay = 0.f, az = 0.f, aw = 0.f;
        #pragma unroll
        for (int s = 0; s < NS; ++s) {
            const int is = __shfl(myidx, s);
            const float4 v = ((const float4*)(ue + (size_t)is * NF))[lane];
            ax += v.x; ay += v.y; az += v.z; aw += v.w;
        }
        const float inv = 1.0f / 11.0f;    // reference divides by S+1
        ushort4 s4, n4;
        s4.x = f2bf(sf.x); s4.y = f2bf(sf.y); s4.z = f2bf(sf.z); s4.w = f2bf(sf.w);
        n4.x = f2bf(ax * inv); n4.y = f2bf(ay * inv);
        n4.z = f2bf(az * inv); n4.w = f2bf(aw * inv);
        *(ushort4*)(crow + lane * 4) = s4;
        *(ushort4*)(crow + NF + lane * 4) = n4;
    } else {                               // zero pad rows (ws is poisoned)
        ushort4 z; z.x = z.y = z.z = z.w = 0;
        *(ushort4*)(crow + lane * 4) = z;
        *(ushort4*)(crow + NF + lane * 4) = z;
    }
}

// K2: out[e][b] = relu(sum_k W[e][k]*comb[b][k]).
// Tile 64(b) x 128(e), BK=32, grid (314,2)=628 blocks (~2.45/CU).
// Double-buffered LDS (A 2x8KB, B 2x4KB), 2-phase pipeline: issue next tile's
// global_load_lds BEFORE computing current; ONE __syncthreads per iter (its
// vmcnt(0)+lgkm drain is the required wait, overlapped with compute).
// Layouts: A [kg4][row128][8], B [kg4][row64][8] -> conflict-free b128 reads.
__global__ __launch_bounds__(256) void gemm_relu(
    const unsigned short* __restrict__ wbf,   // [256][512] bf16
    const unsigned short* __restrict__ comb,  // [B_PAD][512] bf16
    float* __restrict__ out)                  // [256][20000] f32
{
    __shared__ unsigned short Alds[2][4096];  // 2 x 8 KB
    __shared__ unsigned short Blds[2][2048];  // 2 x 4 KB
    const int t    = threadIdx.x;
    const int lane = t & 63;
    const int wv   = t >> 6;                  // wave owns e-rows [wv*32, wv*32+32)
    const int n0   = blockIdx.x * 64;         // b-tile
    const int m0   = blockIdx.y * 128;        // e-tile
    const int fr   = lane & 15;
    const int kq   = lane >> 4;

    // staging coords
    const int arow = t & 127, akg = t >> 7;   // A: 2 issues (kg, kg+2)
    const int brow = t & 63,  bkg = t >> 6;   // B: 1 issue

    const unsigned short* gaBase = wbf  + (size_t)(m0 + arow) * K2 + akg * 8;
    const unsigned short* gbBase = comb + (size_t)(n0 + brow) * K2 + bkg * 8;

#define STAGE(nb, ks)                                                            \
    do {                                                                         \
        const unsigned short* ga = gaBase + (ks) * 32;                           \
        const unsigned short* gb = gbBase + (ks) * 32;                           \
        __builtin_amdgcn_global_load_lds(                                        \
            (const __attribute__((address_space(1))) void*)ga,                   \
            (__attribute__((address_space(3))) void*)(&Alds[nb][0] + t * 8),     \
            16, 0, 0);                                                           \
        __builtin_amdgcn_global_load_lds(                                        \
            (const __attribute__((address_space(1))) void*)(ga + 16),            \
            (__attribute__((address_space(3))) void*)(&Alds[nb][2048] + t * 8),  \
            16, 0, 0);                                                           \
        __builtin_amdgcn_global_load_lds(                                        \
            (const __attribute__((address_space(1))) void*)gb,                   \
            (__attribute__((address_space(3))) void*)(&Blds[nb][0] + t * 8),     \
            16, 0, 0);                                                           \
    } while (0)

    f32x4 acc[2][4] = {};

    STAGE(0, 0);
    __syncthreads();

    #pragma unroll
    for (int ks = 0; ks < 16; ++ks) {
        const int cur = ks & 1;
        if (ks < 15) STAGE(cur ^ 1, ks + 1);

        const short8* A8 = (const short8*)Alds[cur];
        const short8* B8 = (const short8*)Blds[cur];
        short8 af[2], bg[4];
        #pragma unroll
        for (int i = 0; i < 2; ++i)
            af[i] = A8[kq * 128 + wv * 32 + i * 16 + fr];
        #pragma unroll
        for (int j = 0; j < 4; ++j)
            bg[j] = B8[kq * 64 + j * 16 + fr];
        #pragma unroll
        for (int i = 0; i < 2; ++i)
            #pragma unroll
            for (int j = 0; j < 4; ++j)
                acc[i][j] = __builtin_amdgcn_mfma_f32_16x16x32_bf16(af[i], bg[j], acc[i][j], 0, 0, 0);

        __syncthreads();   // drains vmcnt(0)+lgkm: next tile staged, this buf free
    }
#undef STAGE

    // ---- epilogue: relu + store ----
    #pragma unroll
    for (int i = 0; i < 2; ++i) {
        const int e = m0 + wv * 32 + i * 16 + kq * 4;
        #pragma unroll
        for (int j = 0; j < 4; ++j) {
            const int b = n0 + j * 16 + fr;
            if (b < B_TOTAL) {
                #pragma unroll
                for (int r = 0; r < 4; ++r)
                    out[(size_t)(e + r) * B_TOTAL + b] = fmaxf(acc[i][j][r], 0.0f);
            }
        }
    }
}

extern "C" void kernel_launch(void* const* d_in, const int* in_sizes, int n_in,
                              void* d_out, int out_size, void* d_ws, size_t ws_size,
                              hipStream_t stream) {
    const float* ue    = (const float*)d_in[0];
    // d_in[1] = features_ap: unused (ue2ue mode)
    const int*   nidx  = (const int*)d_in[2];
    const int*   nodes = (const int*)d_in[3];
    const float* w     = (const float*)d_in[4];
    float*       out   = (float*)d_out;

    unsigned short* comb = (unsigned short*)d_ws;              // [B_PAD][512] bf16 = 20.58 MB
    unsigned short* wbf  = comb + (size_t)B_PAD * K2;          // [256][512] bf16  = 0.26 MB

    hipLaunchKernelGGL(gather_combine, dim3(B_PAD / 4), dim3(256), 0, stream,
                       ue, nidx, nodes, w, comb, wbf);
    hipLaunchKernelGGL(gemm_relu, dim3(B_PAD / 64, 2), dim3(256), 0, stream,
                       wbf, comb, out);
}